// Round 13
// baseline (1304.191 us; speedup 1.0000x reference)
//
#include <hip/hip_runtime.h>
#include <cstdint>
#include <cmath>

#define NN 8192
#define DD 512
#define KP1 31                      // k+1 with k=30
#define HALF_EDGES (NN * KP1)       // 253952

typedef float v2f __attribute__((ext_vector_type(2)));

// ---------------- Threefry-2x32-20, key = (0, 42) --------------------------
__device__ __forceinline__ uint32_t rotl32(uint32_t v, int s) {
  return (v << s) | (v >> (32 - s));
}

__device__ __forceinline__ void threefry2x32_42(uint32_t x0, uint32_t x1,
                                                uint32_t& o0, uint32_t& o1) {
  const uint32_t ks0 = 0u, ks1 = 42u;
  const uint32_t ks2 = 0x1BD11BDAu ^ ks0 ^ ks1;
  x0 += ks0; x1 += ks1;
  x0 += x1; x1 = rotl32(x1, 13); x1 ^= x0;
  x0 += x1; x1 = rotl32(x1, 15); x1 ^= x0;
  x0 += x1; x1 = rotl32(x1, 26); x1 ^= x0;
  x0 += x1; x1 = rotl32(x1, 6);  x1 ^= x0;
  x0 += ks1; x1 += ks2 + 1u;
  x0 += x1; x1 = rotl32(x1, 17); x1 ^= x0;
  x0 += x1; x1 = rotl32(x1, 29); x1 ^= x0;
  x0 += x1; x1 = rotl32(x1, 16); x1 ^= x0;
  x0 += x1; x1 = rotl32(x1, 24); x1 ^= x0;
  x0 += ks2; x1 += ks0 + 2u;
  x0 += x1; x1 = rotl32(x1, 13); x1 ^= x0;
  x0 += x1; x1 = rotl32(x1, 15); x1 ^= x0;
  x0 += x1; x1 = rotl32(x1, 26); x1 ^= x0;
  x0 += x1; x1 = rotl32(x1, 6);  x1 ^= x0;
  x0 += ks0; x1 += ks1 + 3u;
  x0 += x1; x1 = rotl32(x1, 17); x1 ^= x0;
  x0 += x1; x1 = rotl32(x1, 29); x1 ^= x0;
  x0 += x1; x1 = rotl32(x1, 16); x1 ^= x0;
  x0 += x1; x1 = rotl32(x1, 24); x1 ^= x0;
  x0 += ks1; x1 += ks2 + 4u;
  x0 += x1; x1 = rotl32(x1, 13); x1 ^= x0;
  x0 += x1; x1 = rotl32(x1, 15); x1 ^= x0;
  x0 += x1; x1 = rotl32(x1, 26); x1 ^= x0;
  x0 += x1; x1 = rotl32(x1, 6);  x1 ^= x0;
  x0 += ks2; x1 += ks0 + 5u;
  o0 = x0; o1 = x1;
}

__device__ __forceinline__ bool keep_edge(uint32_t e) {
  uint32_t y0, y1;
  threefry2x32_42(0u, e, y0, y1);
  uint32_t bits = y0 ^ y1;
  float u = __uint_as_float((bits >> 9) | 0x3f800000u) - 1.0f;
  return u < 0.9f;
}

// ---------------- K1: fp32 row norm (numpy pairwise tree) ------------------
__global__ __launch_bounds__(256) void rownorm_kernel(const float* __restrict__ x,
                                                      float* __restrict__ nrm) {
#pragma clang fp contract(off)
  __shared__ float rowbuf[16][DD];
  __shared__ float partial[16][4];
  int tid = threadIdx.x;
  int rowbase = blockIdx.x * 16;

  for (int p = 0; p < 8; ++p) {
    int f = tid + p * 256;
    int r = f >> 7, k4 = f & 127;
    *(float4*)(&rowbuf[r][k4 << 2]) =
        *(const float4*)(x + (size_t)(rowbase + r) * DD + (k4 << 2));
  }
  __syncthreads();
  if (tid < 64) {
    int r = tid >> 2, q = tid & 3;
    const float* s = &rowbuf[r][q * 128];
    float a0 = s[0]*s[0], a1 = s[1]*s[1], a2 = s[2]*s[2], a3 = s[3]*s[3];
    float a4 = s[4]*s[4], a5 = s[5]*s[5], a6 = s[6]*s[6], a7 = s[7]*s[7];
    for (int i = 8; i < 128; i += 8) {
      a0 += s[i+0]*s[i+0]; a1 += s[i+1]*s[i+1];
      a2 += s[i+2]*s[i+2]; a3 += s[i+3]*s[i+3];
      a4 += s[i+4]*s[i+4]; a5 += s[i+5]*s[i+5];
      a6 += s[i+6]*s[i+6]; a7 += s[i+7]*s[i+7];
    }
    partial[r][q] = ((a0 + a1) + (a2 + a3)) + ((a4 + a5) + (a6 + a7));
  }
  __syncthreads();
  if (tid < 16) {
    float S = (partial[tid][0] + partial[tid][1]) + (partial[tid][2] + partial[tid][3]);
    nrm[rowbase + tid] = sqrtf(S);
  }
}

// ---------------- K2: upper-triangular 128x128 sim GEMM, packed f32 --------
// Compact launch: 2080 blocks, bid -> (by, bx), bx >= by; off-diag tiles
// written straight + transposed (sim bitwise symmetric). Accumulators are
// <2 x float> pairs across the j (column) dimension -> v_pk_mul_f32 +
// v_pk_add_f32; each half rounds identically to the scalar sequential
// mul+add chain over ascending k (verified R8 contract; fp contract off).
__global__ __launch_bounds__(256, 2) void gemm_kernel(const float* __restrict__ x,
                                                      const float* __restrict__ nrm,
                                                      float* __restrict__ out) {
#pragma clang fp contract(off)
  // ---- triangular block index
  int bid = blockIdx.x;
  int by = (int)((129.0f - sqrtf(16641.0f - 8.0f * (float)bid)) * 0.5f);
  while (64 * by - (by * (by - 1)) / 2 > bid) --by;
  while (64 * (by + 1) - ((by + 1) * by) / 2 <= bid) ++by;
  const int bx = by + (bid - (64 * by - (by * (by - 1)) / 2));

  extern __shared__ char smem[];
  float4* AsF4 = (float4*)smem;              // [128 rows][16 slots]  32 KB
  float4* BsF4 = (float4*)(smem + 32768);    // [128 cols][16 slots]  32 KB

  const int tid = threadIdx.x;
  const int rb = by * 128;
  const int cb = bx * 128;
  const int m = tid & 15;
  const int g = tid >> 4;

  float nA[8], nB[8];
  #pragma unroll
  for (int p = 0; p < 8; ++p) {
    nA[p] = nrm[rb + g + 16 * p];
    nB[p] = nrm[cb + g + 16 * p];
  }

  const int lane = tid & 63, wave = tid >> 6;
  const int wr = wave >> 1, wc = wave & 1;
  const int lr = lane >> 3, lc = lane & 7;
  const int r0 = wr * 64 + lr * 8;
  const int c0 = wc * 64 + lc;
  const int rsw = r0 >> 3;

  v2f acc2[8][4];                            // [i][pair], pair p = cols j=2p,2p+1
  #pragma unroll
  for (int i = 0; i < 8; ++i)
    #pragma unroll
    for (int p = 0; p < 4; ++p) acc2[i][p] = (v2f){0.f, 0.f};

  const float4* xv = (const float4*)x;

  float4 ra[8], rbv[8];
  #pragma unroll
  for (int p = 0; p < 8; ++p) {
    int r = g + 16 * p;
    ra[p]  = xv[(size_t)(rb + r) * 128 + m];
    rbv[p] = xv[(size_t)(cb + r) * 128 + m];
  }

  for (int kc = 0; kc < 8; ++kc) {
    __syncthreads();
    #pragma unroll
    for (int p = 0; p < 8; ++p) {
      int r = g + 16 * p;
      float4 va = ra[p];
      va.x = va.x / nA[p]; va.y = va.y / nA[p];
      va.z = va.z / nA[p]; va.w = va.w / nA[p];
      AsF4[r * 16 + ((m + (r >> 3)) & 15)] = va;
      float4 vb = rbv[p];
      vb.x = vb.x / nB[p]; vb.y = vb.y / nB[p];
      vb.z = vb.z / nB[p]; vb.w = vb.w / nB[p];
      BsF4[r * 16 + ((m + r) & 15)] = vb;
    }
    __syncthreads();
    if (kc < 7) {
      #pragma unroll
      for (int p = 0; p < 8; ++p) {
        int r = g + 16 * p;
        ra[p]  = xv[(size_t)(rb + r) * 128 + (kc + 1) * 16 + m];
        rbv[p] = xv[(size_t)(cb + r) * 128 + (kc + 1) * 16 + m];
      }
    }

    #pragma unroll 2
    for (int k4 = 0; k4 < 16; ++k4) {
      float4 av[8], bv[8];
      int tA = (k4 + rsw) & 15;
      #pragma unroll
      for (int i = 0; i < 8; ++i) av[i] = AsF4[(r0 + i) * 16 + tA];
      #pragma unroll
      for (int j = 0; j < 8; ++j)
        bv[j] = BsF4[(c0 + 8 * j) * 16 + ((k4 + lc + 8 * j) & 15)];
      #pragma unroll
      for (int kk = 0; kk < 4; ++kk) {
        v2f bp[4];
        #pragma unroll
        for (int p = 0; p < 4; ++p)
          bp[p] = (v2f){((const float*)&bv[2 * p])[kk],
                        ((const float*)&bv[2 * p + 1])[kk]};
        #pragma unroll
        for (int i = 0; i < 8; ++i) {
          float a = ((const float*)&av[i])[kk];
          v2f a2 = (v2f){a, a};
          #pragma unroll
          for (int p = 0; p < 4; ++p)
            acc2[i][p] = acc2[i][p] + a2 * bp[p];  // v_pk_mul + v_pk_add
        }
      }
    }
  }

  // Write-out via LDS re-tile (stride 129): straight + transposed (off-diag).
  float* Cs = (float*)smem;
  float4* outv = (float4*)out;
  const bool offdiag = (rb != cb);
  for (int half = 0; half < 2; ++half) {
    __syncthreads();
    if (wr == half) {
      #pragma unroll
      for (int i = 0; i < 8; ++i)
        #pragma unroll
        for (int j = 0; j < 8; ++j)
          Cs[(lr * 8 + i) * 129 + wc * 64 + 8 * j + lc] =
              ((const float*)&acc2[i][j >> 1])[j & 1];
    }
    __syncthreads();
    #pragma unroll
    for (int q = 0; q < 8; ++q) {
      int f2 = tid + q * 256;
      int rl = f2 >> 5, c4 = f2 & 31;
      float4 o;
      o.x = Cs[rl * 129 + 4 * c4 + 0];
      o.y = Cs[rl * 129 + 4 * c4 + 1];
      o.z = Cs[rl * 129 + 4 * c4 + 2];
      o.w = Cs[rl * 129 + 4 * c4 + 3];
      outv[(size_t)(rb + half * 64 + rl) * 2048 + (cb >> 2) + c4] = o;
    }
    if (offdiag) {
      #pragma unroll
      for (int q = 0; q < 8; ++q) {
        int f2 = tid + q * 256;
        int c = f2 >> 4, t4 = f2 & 15;
        float4 o;
        o.x = Cs[(4 * t4 + 0) * 129 + c];
        o.y = Cs[(4 * t4 + 1) * 129 + c];
        o.z = Cs[(4 * t4 + 2) * 129 + c];
        o.w = Cs[(4 * t4 + 3) * 129 + c];
        outv[(size_t)(cb + c) * 2048 + ((rb + half * 64) >> 2) + t4] = o;
      }
    }
  }
}

// ---------------- K3: per-row top-31, lane-registered O(1) insertion -------
__global__ __launch_bounds__(256) void topk_kernel(const float* __restrict__ sim,
                                                   float* __restrict__ vals,
                                                   int* __restrict__ inds) {
  const int w = threadIdx.x >> 6;
  const int lane = threadIdx.x & 63;
  const int row = blockIdx.x * 4 + w;

  float kval = -1e30f;
  int   kidx = 0;
  float kmin = -1e30f;

  const float* srow = sim + (size_t)row * NN;
  for (int grp = 0; grp < NN / 64; ++grp) {
    float v = srow[grp * 64 + lane];
    unsigned long long mask = __ballot(v > kmin);
    while (mask) {
      int src = __builtin_ctzll(mask);
      mask &= mask - 1;
      float vv = __shfl(v, src, 64);
      if (vv > kmin) {
        int cc = grp * 64 + src;
        unsigned long long ge = __ballot(kval >= vv) & 0x7FFFFFFFull;
        int pos = __popcll(ge);
        float upv = __shfl_up(kval, 1, 64);
        int   upi = __shfl_up(kidx, 1, 64);
        if (lane < KP1) {
          if (lane == pos) { kval = vv; kidx = cc; }
          else if (lane > pos) { kval = upv; kidx = upi; }
        }
        kmin = __shfl(kval, KP1 - 1, 64);
      }
    }
  }
  if (lane < KP1) {
    vals[(size_t)row * KP1 + lane] = kval;
    inds[row * KP1 + lane] = kidx;
  }
}

// ---------------- K4: degree mass (norm_row + norm_col) --------------------
__global__ __launch_bounds__(256) void norm_kernel(const float* __restrict__ vals,
                                                   const int* __restrict__ inds,
                                                   float* __restrict__ norm) {
  int i = blockIdx.x * blockDim.x + threadIdx.x;
  if (i >= NN) return;
  float s = 0.f;
  for (int t = 0; t < KP1; ++t) {
    float v = vals[i * KP1 + t];
    s += v;
    atomicAdd(&norm[inds[i * KP1 + t]], v);
  }
  atomicAdd(&norm[i], s);
}

// ---------------- K5: normalize + relu + threefry dropout + scatter --------
__global__ __launch_bounds__(256) void scatter_kernel(const float* __restrict__ vals,
                                                      const int* __restrict__ inds,
                                                      const float* __restrict__ norm,
                                                      float* __restrict__ out) {
  int e = blockIdx.x * blockDim.x + threadIdx.x;
  if (e >= HALF_EDGES) return;
  int i = e / KP1;
  int c = inds[e];
  float v = vals[e];
  float nv = v * (1.0f / sqrtf(norm[i])) * (1.0f / sqrtf(norm[c]));
  if (isnan(nv)) nv = 0.f;
  nv = fmaxf(nv, 0.f);
  float scaled = nv / 0.9f;
  if (keep_edge((uint32_t)e))
    atomicAdd(out + (size_t)i * NN + c, scaled);
  if (keep_edge((uint32_t)(e + HALF_EDGES)))
    atomicAdd(out + (size_t)c * NN + i, scaled);
}

// ---------------------------------------------------------------------------
extern "C" void kernel_launch(void* const* d_in, const int* in_sizes, int n_in,
                              void* d_out, int out_size, void* d_ws, size_t ws_size,
                              hipStream_t stream) {
  (void)in_sizes; (void)n_in; (void)ws_size;
  const float* x = (const float*)d_in[0];
  float* out = (float*)d_out;

  // ws layout (~2.1 MB, within proven budget)
  float* nrm  = (float*)d_ws;                  // 8192 floats
  float* vals = nrm + NN;                      // 253952 floats
  int*   inds = (int*)(vals + HALF_EDGES);     // 253952 ints
  float* norm = (float*)(inds + HALF_EDGES);   // 8192 floats

  hipLaunchKernelGGL(rownorm_kernel, dim3(NN / 16), dim3(256), 0, stream, x, nrm);
  // sims -> d_out (256 MB scratch, consumed by topk before the final memset)
  hipLaunchKernelGGL(gemm_kernel, dim3(2080), dim3(256), 65536, stream,
                     x, nrm, out);
  hipLaunchKernelGGL(topk_kernel, dim3(NN / 4), dim3(256), 0, stream,
                     out, vals, inds);
  hipMemsetAsync(norm, 0, NN * sizeof(float), stream);
  hipLaunchKernelGGL(norm_kernel, dim3((NN + 255) / 256), dim3(256), 0, stream,
                     vals, inds, norm);
  hipMemsetAsync(d_out, 0, (size_t)out_size * sizeof(float), stream);
  hipLaunchKernelGGL(scatter_kernel, dim3((HALF_EDGES + 255) / 256), dim3(256), 0, stream,
                     vals, inds, norm, out);
}